// Round 5
// baseline (759.903 us; speedup 1.0000x reference)
//
#include <hip/hip_runtime.h>
#include <hip/hip_bf16.h>

typedef __attribute__((ext_vector_type(8))) short sh8;        // 8 x bf16 bits (4 VGPR)
typedef __attribute__((ext_vector_type(16))) float fx16;      // MFMA 32x32 accumulator
typedef __attribute__((ext_vector_type(4))) unsigned int u32x4;

__device__ __forceinline__ unsigned short f2bits(float a) {
  union { __hip_bfloat16 h; unsigned short u; } c;
  c.h = __float2bfloat16(a);
  return c.u;
}
__device__ __forceinline__ unsigned int pk2(float a, float b) {
  return (unsigned int)f2bits(a) | ((unsigned int)f2bits(b) << 16);
}
__device__ __forceinline__ fx16 fzero16() {
  fx16 z;
  #pragma unroll
  for (int i = 0; i < 16; ++i) z[i] = 0.0f;
  return z;
}

// v_permlane32_swap_b32 a, b:  post: a = {a.lo, b.lo}, b = {a.hi_old, b.hi}
#define SWAP32(a, b) asm volatile("v_permlane32_swap_b32 %0, %1" : "+v"(a), "+v"(b))

// ---------------------------------------------------------------------------
// Kernel 1: batched Cayley transform Q = (I-A)(I+A)^-1 for P1 (64) and P2 (64).
// ---------------------------------------------------------------------------
__global__ void k_cayley(const float* __restrict__ P1, const float* __restrict__ P2,
                         float* __restrict__ Qout) {
  int t = blockIdx.x * blockDim.x + threadIdx.x;
  int mat = t >> 4;
  int row = t & 15;
  if (mat >= 128) return;
  const float* P = (mat < 64) ? (P1 + mat * 256) : (P2 + (mat - 64) * 256);
  float M[16], Rr[16];
  #pragma unroll
  for (int j = 0; j < 16; ++j) {
    float a = 0.0f;
    if (j > row) a = P[row * 16 + j];
    if (j < row) a = -P[j * 16 + row];
    float d = (j == row) ? 1.0f : 0.0f;
    M[j]  = d + a;
    Rr[j] = d - a;
  }
  int gbase = (threadIdx.x & 63) & ~15;
  #pragma unroll
  for (int k = 0; k < 16; ++k) {
    float pkk = __shfl(M[k], gbase + k);
    float inv = 1.0f / pkk;
    float pM[16], pR[16];
    #pragma unroll
    for (int j = 0; j < 16; ++j) {
      pM[j] = __shfl(M[j], gbase + k) * inv;
      pR[j] = __shfl(Rr[j], gbase + k) * inv;
    }
    if (row == k) {
      #pragma unroll
      for (int j = 0; j < 16; ++j) { M[j] = pM[j]; Rr[j] = pR[j]; }
    } else {
      float f = M[k];
      #pragma unroll
      for (int j = 0; j < 16; ++j) { M[j] -= f * pM[j]; Rr[j] -= f * pR[j]; }
    }
  }
  float* qo = Qout + mat * 256 + row * 16;
  #pragma unroll
  for (int j = 0; j < 16; ++j) qo[j] = Rr[j];
}

// ---------------------------------------------------------------------------
// Kernel 2: build folded weights in bf16, MFMA B-fragment order.
// W[t2][tile(2)][kstep(4)][lane(64)][r(8)] bf16;
// element = B[k = kstep*16 + (lane>>5)*8 + r, n = tile*32 + (lane&31)].
// ---------------------------------------------------------------------------
__global__ void k_build(const float* __restrict__ P0, const float* __restrict__ P3,
                        const float* __restrict__ Qbuf,
                        unsigned short* __restrict__ W1, unsigned short* __restrict__ W2) {
  int t = blockIdx.x * blockDim.x + threadIdx.x;
  if (t >= 131072) return;
  const float* Q1 = Qbuf;
  const float* Q2 = Qbuf + 16384;
  int e  = t & 65535;
  int r  = e & 7;
  int l  = (e >> 3) & 63;
  int kx = (e >> 9) & 3;
  int mt = (e >> 11) & 1;
  int t2 = (e >> 12) & 15;
  int h8 = ((l >> 5) << 3);
  float acc = 0.0f;
  if (t < 65536) {
    int m = mt * 32 + (l & 31);
    int q = kx * 16 + h8 + r;
    int j0 = m >> 3, j1 = m & 7, i0 = q >> 3, i1 = q & 7;
    #pragma unroll
    for (int t1 = 0; t1 < 16; ++t1) {
      float c0 = P0[(j0 * 8 + (t1 >> 1)) * 16 + ((t1 & 1) * 8 + i0)];
      int a1 = j1 * 16 + t2, u1 = t1 * 8 + i1;
      float c1 = Q1[((a1 & 7) * 8 + (u1 >> 4)) * 256 + (a1 >> 3) * 16 + (u1 & 15)];
      acc += c0 * c1;
    }
    W1[e] = f2bits(acc);
  } else {
    int n = mt * 32 + (l & 31);
    int s = kx * 16 + h8 + r;
    int j2 = n >> 3, j3 = n & 7, i2 = s >> 3, i3 = s & 7;
    #pragma unroll
    for (int t3 = 0; t3 < 16; ++t3) {
      int a2 = j2 * 16 + t3, u2 = t2 * 8 + i2;
      float c2 = Q2[((a2 & 7) * 8 + (u2 >> 4)) * 256 + (a2 >> 3) * 16 + (u2 & 15)];
      float c3 = P3[((t3 & 7) * 8 + i3) * 16 + (j3 * 2 + (t3 >> 3))];
      acc += c2 * c3;
    }
    W2[e] = f2bits(acc);
  }
}

// ---------------------------------------------------------------------------
// Kernel 3: phase-split fused main. One elem at a time per WG (4 elems/WG):
//  phase1: 4 waves build Y-half (t2-slices 8, K=512) = A-frags written to LDS
//          in FRAGMENT ORDER (conflict-free by construction; reader lane ==
//          writer lane).
//  phase2: long-K GEMM out += Yr_half @ B23_half; wave = (m-half, K-half);
//          each Y-frag read exactly once. K-halves reduced via LDS scratch.
// LDS 72 KB -> 2 WGs/CU which anti-phase (one WG's pack overlaps the other's
// MFMA). Weights stream from L2 (256 KB, FETCH-free).
// ---------------------------------------------------------------------------
__global__ __launch_bounds__(256, 2) void k_main(
    const float* __restrict__ x,
    const unsigned short* __restrict__ W1,
    const unsigned short* __restrict__ W2,
    const float* __restrict__ bias,
    float* __restrict__ out) {
  __shared__ __align__(16) char smem[8192 + 65536];
  char* XsT = smem;              // [64 s][128 B] current elem X^T bf16, swizzled
  char* Yf  = smem + 8192;       // [mt(2)][kq(32)][lane(64)][16 B] A-frags (one half)

  const int tid  = threadIdx.x;
  const int lane = tid & 63;
  const int w    = tid >> 6;
  const int h    = lane >> 5;
  const int l31  = lane & 31;
  const int mh   = w >> 1;       // phase2: m-half
  const int kh   = w & 1;        // phase2: K-half

  const sh8* w1f = (const sh8*)W1;   // idx: t2*512 + (tile*4+kstep)*64 + lane
  const sh8* w2f = (const sh8*)W2;
  const fx16 zc = fzero16();

  for (int e = 0; e < 4; ++e) {
    const size_t b = (size_t)blockIdx.x * 4 + e;

    // ---- stage X_b (all 256 threads: s = tid&63, one 16-q chunk each) ----
    {
      const int s = tid & 63;
      const int c = tid >> 6;                   // q-chunk 0..3
      const float* xb = x + b * 4096;
      const unsigned sw = ((unsigned)(s & 7)) << 4;
      unsigned int d[8];
      #pragma unroll
      for (int jj = 0; jj < 8; ++jj) {
        float a  = xb[(c * 16 + 2 * jj + 0) * 64 + s];
        float bq = xb[(c * 16 + 2 * jj + 1) * 64 + s];
        d[jj] = pk2(a, bq);
      }
      u32x4 v0 = {d[0], d[1], d[2], d[3]};
      u32x4 v1 = {d[4], d[5], d[6], d[7]};
      char* base = XsT + s * 128;
      *(u32x4*)(base + (((unsigned)(c * 32)) ^ sw))      = v0;
      *(u32x4*)(base + (((unsigned)(c * 32 + 16)) ^ sw)) = v1;
    }
    __syncthreads();                            // X ready; prev elem's Yf free

    // ---- GEMM1 A-frags for this elem (8 ds_read_b128) ----
    sh8 af[2][4];
    #pragma unroll
    for (int st = 0; st < 2; ++st)
      #pragma unroll
      for (int kq = 0; kq < 4; ++kq) {
        int srow = st * 32 + l31;
        unsigned boff = (unsigned)srow * 128 +
                        (((unsigned)(kq * 32 + h * 16)) ^ (((unsigned)(srow & 7)) << 4));
        af[st][kq] = *(const sh8*)(XsT + boff);
      }

    fx16 accA[2], accB[2];                     // K-half partial out (this wave)
    accA[0] = zc; accA[1] = zc; accB[0] = zc; accB[1] = zc;

    #pragma unroll
    for (int half = 0; half < 2; ++half) {
      // ================= phase 1: build Y-half, write frags ================
      #pragma unroll
      for (int tt = 0; tt < 2; ++tt) {
        const int t2l = w * 2 + tt;            // 0..7
        const int t2  = half * 8 + t2l;

        sh8 b1[2][4];
        #pragma unroll
        for (int mt = 0; mt < 2; ++mt)
          #pragma unroll
          for (int kq = 0; kq < 4; ++kq)
            b1[mt][kq] = w1f[t2 * 512 + (mt * 4 + kq) * 64 + lane];

        fx16 accY[2][2];
        __builtin_amdgcn_s_setprio(1);
        #pragma unroll
        for (int st = 0; st < 2; ++st)
          #pragma unroll
          for (int mt = 0; mt < 2; ++mt) {
            accY[st][mt] = __builtin_amdgcn_mfma_f32_32x32x16_bf16(af[st][0], b1[mt][0], zc, 0, 0, 0);
            #pragma unroll
            for (int kq = 1; kq < 4; ++kq)
              accY[st][mt] = __builtin_amdgcn_mfma_f32_32x32x16_bf16(af[st][kq], b1[mt][kq], accY[st][mt], 0, 0, 0);
          }
        __builtin_amdgcn_s_setprio(0);

        // pack + frag-order LDS write: frag (st,c) -> Yf[mt][t2l*4+st*2+c][lane]
        #pragma unroll
        for (int st = 0; st < 2; ++st)
          #pragma unroll
          for (int mt = 0; mt < 2; ++mt) {
            fx16 Y = accY[st][mt];
            unsigned int P0 = pk2(Y[0],  Y[1]),  P1 = pk2(Y[2],  Y[3]);
            unsigned int P2 = pk2(Y[4],  Y[5]),  P3 = pk2(Y[6],  Y[7]);
            unsigned int P4 = pk2(Y[8],  Y[9]),  P5 = pk2(Y[10], Y[11]);
            unsigned int P6 = pk2(Y[12], Y[13]), P7 = pk2(Y[14], Y[15]);
            SWAP32(P0, P2); SWAP32(P1, P3);
            SWAP32(P4, P6); SWAP32(P5, P7);
            const int kqb = t2l * 4 + st * 2;
            *(u32x4*)(Yf + (((mt * 32 + kqb + 0) * 64 + lane) << 4)) = (u32x4){P0, P1, P2, P3};
            *(u32x4*)(Yf + (((mt * 32 + kqb + 1) * 64 + lane) << 4)) = (u32x4){P4, P5, P6, P7};
          }
      }
      __syncthreads();                          // Y-half frags visible

      // ================= phase 2: out += Yr_half @ B23_half ================
      __builtin_amdgcn_s_setprio(1);
      #pragma unroll
      for (int i = 0; i < 16; ++i) {
        const int kq  = kh * 16 + i;            // frag index within half
        const int t2  = half * 8 + (kq >> 2);
        const int ksl = kq & 3;
        sh8 a = *(const sh8*)(Yf + (((mh * 32 + kq) * 64 + lane) << 4));
        sh8 bf0 = w2f[t2 * 512 + (ksl)       * 64 + lane];   // nt=0
        sh8 bf1 = w2f[t2 * 512 + (4 + ksl)   * 64 + lane];   // nt=1
        if (i & 1) {
          accB[0] = __builtin_amdgcn_mfma_f32_32x32x16_bf16(a, bf0, accB[0], 0, 0, 0);
          accB[1] = __builtin_amdgcn_mfma_f32_32x32x16_bf16(a, bf1, accB[1], 0, 0, 0);
        } else {
          accA[0] = __builtin_amdgcn_mfma_f32_32x32x16_bf16(a, bf0, accA[0], 0, 0, 0);
          accA[1] = __builtin_amdgcn_mfma_f32_32x32x16_bf16(a, bf1, accA[1], 0, 0, 0);
        }
      }
      __builtin_amdgcn_s_setprio(0);
      __syncthreads();                          // Yf consumed (next half reuses)
    }

    // ---- fold K-parity chains; reduce K-halves via LDS scratch ----
    fx16 accO[2];
    #pragma unroll
    for (int nt = 0; nt < 2; ++nt) {
      #pragma unroll
      for (int r = 0; r < 16; ++r) accA[nt][r] += accB[nt][r];
      accO[nt] = accA[nt];
      accA[nt] = zc; accB[nt] = zc;             // reset for next elem
    }

    float* red = (float*)Yf;                    // scratch: [(mh*2+nt)*4+rc][lane] f32x4
    if (kh == 1) {
      #pragma unroll
      for (int nt = 0; nt < 2; ++nt)
        #pragma unroll
        for (int rc = 0; rc < 4; ++rc) {
          u32x4 v;
          #pragma unroll
          for (int j = 0; j < 4; ++j) v[j] = __float_as_uint(accO[nt][rc * 4 + j]);
          *(u32x4*)(red + ((mh * 2 + nt) * 4 + rc) * 64 * 4 + lane * 4) = v;
        }
    }
    __syncthreads();
    if (kh == 0) {
      float* ob = out + b * 4096;
      #pragma unroll
      for (int nt = 0; nt < 2; ++nt)
        #pragma unroll
        for (int rc = 0; rc < 4; ++rc) {
          u32x4 v = *(const u32x4*)(red + ((mh * 2 + nt) * 4 + rc) * 64 * 4 + lane * 4);
          #pragma unroll
          for (int j = 0; j < 4; ++j) {
            int reg = rc * 4 + j;
            int m = mh * 32 + (reg & 3) + 8 * (reg >> 2) + 4 * h;
            int n = nt * 32 + l31;
            int o = m * 64 + n;
            ob[o] = accO[nt][reg] + __uint_as_float(v[j]) + bias[o];
          }
        }
    }
    // next elem's post-X barrier orders these reads before Yf is rewritten
  }
}

// ---------------------------------------------------------------------------
extern "C" void kernel_launch(void* const* d_in, const int* in_sizes, int n_in,
                              void* d_out, int out_size, void* d_ws, size_t ws_size,
                              hipStream_t stream) {
  (void)n_in; (void)out_size; (void)ws_size;
  const float* x    = (const float*)d_in[0];
  const float* P0   = (const float*)d_in[1];
  const float* P1   = (const float*)d_in[2];
  const float* P2   = (const float*)d_in[3];
  const float* P3   = (const float*)d_in[4];
  const float* bias = (const float*)d_in[5];
  float* out = (float*)d_out;

  // ws: Qbuf f32[128*256] (128 KB) | W1 bf16[65536] (128 KB) | W2 bf16[65536] (128 KB)
  float* Qbuf = (float*)d_ws;
  unsigned short* W1 = (unsigned short*)((char*)d_ws + 131072);
  unsigned short* W2 = (unsigned short*)((char*)d_ws + 262144);

  k_cayley<<<8, 256, 0, stream>>>(P1, P2, Qbuf);
  k_build<<<512, 256, 0, stream>>>(P0, P3, Qbuf, W1, W2);

  int batch = in_sizes[0] / 4096;
  k_main<<<batch / 4, 256, 0, stream>>>(x, W1, W2, bias, out);
}

// Round 6
// 153.743 us; speedup vs baseline: 4.9427x; 4.9427x over previous
//
#include <hip/hip_runtime.h>
#include <hip/hip_bf16.h>

typedef __attribute__((ext_vector_type(8))) short sh8;        // 8 x bf16 bits (4 VGPR)
typedef __attribute__((ext_vector_type(16))) float fx16;      // MFMA 32x32 accumulator
typedef __attribute__((ext_vector_type(4))) unsigned int u32x4;

__device__ __forceinline__ unsigned short f2bits(float a) {
  union { __hip_bfloat16 h; unsigned short u; } c;
  c.h = __float2bfloat16(a);
  return c.u;
}
__device__ __forceinline__ unsigned int pk2(float a, float b) {
  return (unsigned int)f2bits(a) | ((unsigned int)f2bits(b) << 16);
}
__device__ __forceinline__ fx16 fzero16() {
  fx16 z;
  #pragma unroll
  for (int i = 0; i < 16; ++i) z[i] = 0.0f;
  return z;
}

// v_permlane32_swap_b32 a, b:  post: a = {a.lo, b.lo}, b = {a.hi_old, b.hi}
#define SWAP32(a, b) asm volatile("v_permlane32_swap_b32 %0, %1" : "+v"(a), "+v"(b))

// ---------------------------------------------------------------------------
// Kernel 1: batched Cayley transform Q = (I-A)(I+A)^-1 for P1 (64) and P2 (64).
// ---------------------------------------------------------------------------
__global__ void k_cayley(const float* __restrict__ P1, const float* __restrict__ P2,
                         float* __restrict__ Qout) {
  int t = blockIdx.x * blockDim.x + threadIdx.x;
  int mat = t >> 4;
  int row = t & 15;
  if (mat >= 128) return;
  const float* P = (mat < 64) ? (P1 + mat * 256) : (P2 + (mat - 64) * 256);
  float M[16], Rr[16];
  #pragma unroll
  for (int j = 0; j < 16; ++j) {
    float a = 0.0f;
    if (j > row) a = P[row * 16 + j];
    if (j < row) a = -P[j * 16 + row];
    float d = (j == row) ? 1.0f : 0.0f;
    M[j]  = d + a;
    Rr[j] = d - a;
  }
  int gbase = (threadIdx.x & 63) & ~15;
  #pragma unroll
  for (int k = 0; k < 16; ++k) {
    float pkk = __shfl(M[k], gbase + k);
    float inv = 1.0f / pkk;
    float pM[16], pR[16];
    #pragma unroll
    for (int j = 0; j < 16; ++j) {
      pM[j] = __shfl(M[j], gbase + k) * inv;
      pR[j] = __shfl(Rr[j], gbase + k) * inv;
    }
    if (row == k) {
      #pragma unroll
      for (int j = 0; j < 16; ++j) { M[j] = pM[j]; Rr[j] = pR[j]; }
    } else {
      float f = M[k];
      #pragma unroll
      for (int j = 0; j < 16; ++j) { M[j] -= f * pM[j]; Rr[j] -= f * pR[j]; }
    }
  }
  float* qo = Qout + mat * 256 + row * 16;
  #pragma unroll
  for (int j = 0; j < 16; ++j) qo[j] = Rr[j];
}

// ---------------------------------------------------------------------------
// Kernel 2: build folded weights in bf16, MFMA B-fragment order.
// W[t2][tile(2)][kstep(4)][lane(64)][r(8)] bf16;
// element = B[k = kstep*16 + (lane>>5)*8 + r, n = tile*32 + (lane&31)].
// ---------------------------------------------------------------------------
__global__ void k_build(const float* __restrict__ P0, const float* __restrict__ P3,
                        const float* __restrict__ Qbuf,
                        unsigned short* __restrict__ W1, unsigned short* __restrict__ W2) {
  int t = blockIdx.x * blockDim.x + threadIdx.x;
  if (t >= 131072) return;
  const float* Q1 = Qbuf;
  const float* Q2 = Qbuf + 16384;
  int e  = t & 65535;
  int r  = e & 7;
  int l  = (e >> 3) & 63;
  int kx = (e >> 9) & 3;
  int mt = (e >> 11) & 1;
  int t2 = (e >> 12) & 15;
  int h8 = ((l >> 5) << 3);
  float acc = 0.0f;
  if (t < 65536) {
    int m = mt * 32 + (l & 31);
    int q = kx * 16 + h8 + r;
    int j0 = m >> 3, j1 = m & 7, i0 = q >> 3, i1 = q & 7;
    #pragma unroll
    for (int t1 = 0; t1 < 16; ++t1) {
      float c0 = P0[(j0 * 8 + (t1 >> 1)) * 16 + ((t1 & 1) * 8 + i0)];
      int a1 = j1 * 16 + t2, u1 = t1 * 8 + i1;
      float c1 = Q1[((a1 & 7) * 8 + (u1 >> 4)) * 256 + (a1 >> 3) * 16 + (u1 & 15)];
      acc += c0 * c1;
    }
    W1[e] = f2bits(acc);
  } else {
    int n = mt * 32 + (l & 31);
    int s = kx * 16 + h8 + r;
    int j2 = n >> 3, j3 = n & 7, i2 = s >> 3, i3 = s & 7;
    #pragma unroll
    for (int t3 = 0; t3 < 16; ++t3) {
      int a2 = j2 * 16 + t3, u2 = t2 * 8 + i2;
      float c2 = Q2[((a2 & 7) * 8 + (u2 >> 4)) * 256 + (a2 >> 3) * 16 + (u2 & 15)];
      float c3 = P3[((t3 & 7) * 8 + i3) * 16 + (j3 * 2 + (t3 >> 3))];
      acc += c2 * c3;
    }
    W2[e] = f2bits(acc);
  }
}

// ---------------------------------------------------------------------------
// Kernel 3 (R4 base + latency fixes). WG = 4 waves / 4 batch elems. Wave w:
// elem pair ep=(w>>1)*2..+1, m-half mh=w&1. Per t2: 32 MFMA over 2 elems
// sharing one weight set. Load placement hides L2 latency with zero extra
// registers: b2 loads at iter top (regs free since prev GEMM2-e1), b1
// reloads for t2+1 right after its last read (GEMM1-e1). All MFMA clusters
// run 2 independent accumulator chains (st- or nt-alternation).
// Peak live set ~246 regs < 256 cap @ 2 waves/SIMD.
// ---------------------------------------------------------------------------
__global__ __launch_bounds__(256, 2) void k_main(
    const float* __restrict__ x,
    const unsigned short* __restrict__ W1,
    const unsigned short* __restrict__ W2,
    const float* __restrict__ bias,
    float* __restrict__ out) {
  __shared__ __align__(16) char XsT[4 * 8192];   // [elem][64 s][128 B], swizzled

  const int tid  = threadIdx.x;
  const int lane = tid & 63;
  const int w    = tid >> 6;
  const int h    = lane >> 5;
  const int l31  = lane & 31;
  const int ep   = (w >> 1) * 2;   // first elem of this wave's pair
  const int mh   = w & 1;          // m-half this wave owns
  const size_t bbase = (size_t)blockIdx.x * 4;

  // ---- Wave w stages elem w (f32 -> bf16, [s][q] transposed, swizzled) ----
  {
    const int s = lane;
    const float* xb = x + (bbase + w) * 4096;
    const unsigned sw = ((unsigned)(s & 7)) << 4;
    char* base = XsT + w * 8192 + s * 128;
    #pragma unroll
    for (int c = 0; c < 4; ++c) {               // 16 q per chunk
      unsigned int d[8];
      #pragma unroll
      for (int jj = 0; jj < 8; ++jj) {
        float a  = xb[(c * 16 + 2 * jj + 0) * 64 + s];
        float bq = xb[(c * 16 + 2 * jj + 1) * 64 + s];
        d[jj] = pk2(a, bq);
      }
      u32x4 v0 = {d[0], d[1], d[2], d[3]};
      u32x4 v1 = {d[4], d[5], d[6], d[7]};
      *(u32x4*)(base + (((unsigned)(c * 32)) ^ sw))      = v0;
      *(u32x4*)(base + (((unsigned)(c * 32 + 16)) ^ sw)) = v1;
    }
  }
  __syncthreads();

  // ---- Hoist GEMM1 A-frags for both elems (loop-invariant): 16 ds_read_b128
  sh8 af[2][2][4];
  #pragma unroll
  for (int e = 0; e < 2; ++e) {
    const char* myX = XsT + (ep + e) * 8192;
    #pragma unroll
    for (int st = 0; st < 2; ++st)
      #pragma unroll
      for (int kq = 0; kq < 4; ++kq) {
        int srow = st * 32 + l31;
        unsigned boff = (unsigned)srow * 128 +
                        (((unsigned)(kq * 32 + h * 16)) ^ (((unsigned)(srow & 7)) << 4));
        af[e][st][kq] = *(const sh8*)(myX + boff);
      }
  }

  const fx16 zc = fzero16();
  fx16 accO[2][2];                 // [elem][nt]
  accO[0][0] = zc; accO[0][1] = zc;
  accO[1][0] = zc; accO[1][1] = zc;

  const sh8* w1f = (const sh8*)W1;   // idx: t2*512 + (tile*4+kstep)*64 + lane
  const sh8* w2f = (const sh8*)W2;

  // ---- prologue: b1 for t2=0 (single-buffered, reloaded mid-iteration) ----
  sh8 b1[4];
  #pragma unroll
  for (int kq = 0; kq < 4; ++kq)
    b1[kq] = w1f[(mh * 4 + kq) * 64 + lane];

  #pragma unroll 1
  for (int t2 = 0; t2 < 16; ++t2) {
    // ---- top: b2 loads for THIS t2 (regs free since prev GEMM2-e1);
    //      first use ~16 MFMA + 2 packs later => L2 latency hidden ----
    sh8 b2[2][4];
    #pragma unroll
    for (int nt = 0; nt < 2; ++nt)
      #pragma unroll
      for (int ks = 0; ks < 4; ++ks)
        b2[nt][ks] = w2f[t2 * 512 + (nt * 4 + ks) * 64 + lane];

    // ---- GEMM1 elem0: 8 MFMA, 2 chains (st-alternating) ----
    fx16 accY[2];
    __builtin_amdgcn_s_setprio(1);
    accY[0] = __builtin_amdgcn_mfma_f32_32x32x16_bf16(af[0][0][0], b1[0], zc, 0, 0, 0);
    accY[1] = __builtin_amdgcn_mfma_f32_32x32x16_bf16(af[0][1][0], b1[0], zc, 0, 0, 0);
    #pragma unroll
    for (int kq = 1; kq < 4; ++kq) {
      accY[0] = __builtin_amdgcn_mfma_f32_32x32x16_bf16(af[0][0][kq], b1[kq], accY[0], 0, 0, 0);
      accY[1] = __builtin_amdgcn_mfma_f32_32x32x16_bf16(af[0][1][kq], b1[kq], accY[1], 0, 0, 0);
    }
    __builtin_amdgcn_s_setprio(0);

    // ---- pack elem0 -> ga0 ----
    sh8 ga0[4];
    #pragma unroll
    for (int st = 0; st < 2; ++st) {
      fx16 Y = accY[st];
      unsigned int P0 = pk2(Y[0],  Y[1]),  P1 = pk2(Y[2],  Y[3]);
      unsigned int P2 = pk2(Y[4],  Y[5]),  P3 = pk2(Y[6],  Y[7]);
      unsigned int P4 = pk2(Y[8],  Y[9]),  P5 = pk2(Y[10], Y[11]);
      unsigned int P6 = pk2(Y[12], Y[13]), P7 = pk2(Y[14], Y[15]);
      SWAP32(P0, P2); SWAP32(P1, P3);
      SWAP32(P4, P6); SWAP32(P5, P7);
      union { u32x4 u; sh8 s8; } c0, c1;
      c0.u = (u32x4){P0, P1, P2, P3};
      c1.u = (u32x4){P4, P5, P6, P7};
      ga0[st * 2 + 0] = c0.s8;
      ga0[st * 2 + 1] = c1.s8;
    }

    // ---- GEMM1 elem1: 8 MFMA, 2 chains; last reads of b1[cur] ----
    fx16 accZ[2];
    __builtin_amdgcn_s_setprio(1);
    accZ[0] = __builtin_amdgcn_mfma_f32_32x32x16_bf16(af[1][0][0], b1[0], zc, 0, 0, 0);
    accZ[1] = __builtin_amdgcn_mfma_f32_32x32x16_bf16(af[1][1][0], b1[0], zc, 0, 0, 0);
    #pragma unroll
    for (int kq = 1; kq < 4; ++kq) {
      accZ[0] = __builtin_amdgcn_mfma_f32_32x32x16_bf16(af[1][0][kq], b1[kq], accZ[0], 0, 0, 0);
      accZ[1] = __builtin_amdgcn_mfma_f32_32x32x16_bf16(af[1][1][kq], b1[kq], accZ[1], 0, 0, 0);
    }
    __builtin_amdgcn_s_setprio(0);

    // ---- reload b1 for t2+1 into the same regs (WAR-ordered after GEMM1-e1);
    //      covered by GEMM2-e0 + pack-e1 + GEMM2-e1 ----
    {
      const int t2n = (t2 + 1) & 15;
      #pragma unroll
      for (int kq = 0; kq < 4; ++kq)
        b1[kq] = w1f[t2n * 512 + (mh * 4 + kq) * 64 + lane];
    }

    // ---- GEMM2 elem0: 8 MFMA, 2 chains (nt-alternating) ----
    __builtin_amdgcn_s_setprio(1);
    #pragma unroll
    for (int ks = 0; ks < 4; ++ks) {
      accO[0][0] = __builtin_amdgcn_mfma_f32_32x32x16_bf16(ga0[ks], b2[0][ks], accO[0][0], 0, 0, 0);
      accO[0][1] = __builtin_amdgcn_mfma_f32_32x32x16_bf16(ga0[ks], b2[1][ks], accO[0][1], 0, 0, 0);
    }
    __builtin_amdgcn_s_setprio(0);

    // ---- pack elem1 -> ga1 (overlaps GEMM2-e0 drain) ----
    sh8 ga1[4];
    #pragma unroll
    for (int st = 0; st < 2; ++st) {
      fx16 Y = accZ[st];
      unsigned int P0 = pk2(Y[0],  Y[1]),  P1 = pk2(Y[2],  Y[3]);
      unsigned int P2 = pk2(Y[4],  Y[5]),  P3 = pk2(Y[6],  Y[7]);
      unsigned int P4 = pk2(Y[8],  Y[9]),  P5 = pk2(Y[10], Y[11]);
      unsigned int P6 = pk2(Y[12], Y[13]), P7 = pk2(Y[14], Y[15]);
      SWAP32(P0, P2); SWAP32(P1, P3);
      SWAP32(P4, P6); SWAP32(P5, P7);
      union { u32x4 u; sh8 s8; } c0, c1;
      c0.u = (u32x4){P0, P1, P2, P3};
      c1.u = (u32x4){P4, P5, P6, P7};
      ga1[st * 2 + 0] = c0.s8;
      ga1[st * 2 + 1] = c1.s8;
    }

    // ---- GEMM2 elem1: 8 MFMA, 2 chains ----
    __builtin_amdgcn_s_setprio(1);
    #pragma unroll
    for (int ks = 0; ks < 4; ++ks) {
      accO[1][0] = __builtin_amdgcn_mfma_f32_32x32x16_bf16(ga1[ks], b2[0][ks], accO[1][0], 0, 0, 0);
      accO[1][1] = __builtin_amdgcn_mfma_f32_32x32x16_bf16(ga1[ks], b2[1][ks], accO[1][1], 0, 0, 0);
    }
    __builtin_amdgcn_s_setprio(0);
  }

  // ---- epilogue ----
  #pragma unroll
  for (int e = 0; e < 2; ++e) {
    float* ob = out + (bbase + ep + e) * 4096;
    #pragma unroll
    for (int nt = 0; nt < 2; ++nt) {
      #pragma unroll
      for (int reg = 0; reg < 16; ++reg) {
        int m = mh * 32 + (reg & 3) + 8 * (reg >> 2) + 4 * h;
        int n = nt * 32 + l31;
        int o = m * 64 + n;
        ob[o] = accO[e][nt][reg] + bias[o];
      }
    }
  }
}

// ---------------------------------------------------------------------------
extern "C" void kernel_launch(void* const* d_in, const int* in_sizes, int n_in,
                              void* d_out, int out_size, void* d_ws, size_t ws_size,
                              hipStream_t stream) {
  (void)n_in; (void)out_size; (void)ws_size;
  const float* x    = (const float*)d_in[0];
  const float* P0   = (const float*)d_in[1];
  const float* P1   = (const float*)d_in[2];
  const float* P2   = (const float*)d_in[3];
  const float* P3   = (const float*)d_in[4];
  const float* bias = (const float*)d_in[5];
  float* out = (float*)d_out;

  // ws: Qbuf f32[128*256] (128 KB) | W1 bf16[65536] (128 KB) | W2 bf16[65536] (128 KB)
  float* Qbuf = (float*)d_ws;
  unsigned short* W1 = (unsigned short*)((char*)d_ws + 131072);
  unsigned short* W2 = (unsigned short*)((char*)d_ws + 262144);

  k_cayley<<<8, 256, 0, stream>>>(P1, P2, Qbuf);
  k_build<<<512, 256, 0, stream>>>(P0, P3, Qbuf, W1, W2);

  int batch = in_sizes[0] / 4096;
  k_main<<<batch / 4, 256, 0, stream>>>(x, W1, W2, bias, out);
}

// Round 7
// 144.648 us; speedup vs baseline: 5.2535x; 1.0629x over previous
//
#include <hip/hip_runtime.h>
#include <hip/hip_bf16.h>

typedef __attribute__((ext_vector_type(8))) short sh8;        // 8 x bf16 bits (4 VGPR)
typedef __attribute__((ext_vector_type(16))) float fx16;      // MFMA 32x32 accumulator
typedef __attribute__((ext_vector_type(4))) unsigned int u32x4;

__device__ __forceinline__ unsigned short f2bits(float a) {
  union { __hip_bfloat16 h; unsigned short u; } c;
  c.h = __float2bfloat16(a);
  return c.u;
}
// one-instruction RNE pack: lo = cvt(a), hi = cvt(b)
__device__ __forceinline__ unsigned int pkcvt(float a, float b) {
  unsigned int r;
  asm("v_cvt_pk_bf16_f32 %0, %1, %2" : "=v"(r) : "v"(a), "v"(b));
  return r;
}
__device__ __forceinline__ fx16 fzero16() {
  fx16 z;
  #pragma unroll
  for (int i = 0; i < 16; ++i) z[i] = 0.0f;
  return z;
}

// ---------------------------------------------------------------------------
// Kernel 1: batched Cayley transform Q = (I-A)(I+A)^-1 for P1 (64) and P2 (64).
// ---------------------------------------------------------------------------
__global__ void k_cayley(const float* __restrict__ P1, const float* __restrict__ P2,
                         float* __restrict__ Qout) {
  int t = blockIdx.x * blockDim.x + threadIdx.x;
  int mat = t >> 4;
  int row = t & 15;
  if (mat >= 128) return;
  const float* P = (mat < 64) ? (P1 + mat * 256) : (P2 + (mat - 64) * 256);
  float M[16], Rr[16];
  #pragma unroll
  for (int j = 0; j < 16; ++j) {
    float a = 0.0f;
    if (j > row) a = P[row * 16 + j];
    if (j < row) a = -P[j * 16 + row];
    float d = (j == row) ? 1.0f : 0.0f;
    M[j]  = d + a;
    Rr[j] = d - a;
  }
  int gbase = (threadIdx.x & 63) & ~15;
  #pragma unroll
  for (int k = 0; k < 16; ++k) {
    float pkk = __shfl(M[k], gbase + k);
    float inv = 1.0f / pkk;
    float pM[16], pR[16];
    #pragma unroll
    for (int j = 0; j < 16; ++j) {
      pM[j] = __shfl(M[j], gbase + k) * inv;
      pR[j] = __shfl(Rr[j], gbase + k) * inv;
    }
    if (row == k) {
      #pragma unroll
      for (int j = 0; j < 16; ++j) { M[j] = pM[j]; Rr[j] = pR[j]; }
    } else {
      float f = M[k];
      #pragma unroll
      for (int j = 0; j < 16; ++j) { M[j] -= f * pM[j]; Rr[j] -= f * pR[j]; }
    }
  }
  float* qo = Qout + mat * 256 + row * 16;
  #pragma unroll
  for (int j = 0; j < 16; ++j) qo[j] = Rr[j];
}

// ---------------------------------------------------------------------------
// Kernel 2: build folded weights in bf16, MFMA B-fragment order.
// W1[t2][tile(2)][kstep(4)][lane(64)][r(8)]: k-map q = kstep*16 + 8h + r
//   (hardware-natural; matches X^T LDS frag reads).
// W2[t2][tile(2)][kstep(4)][lane(64)][r(8)]: k-map s = kstep*16 + sigma(h,r),
//   sigma(h,r) = (r&3) + 8*(r>>2) + 4h  -- Y's natural C/D residency, so the
//   GEMM2 A-frag is accY regs in order, NO cross-lane permute needed.
// ---------------------------------------------------------------------------
__global__ void k_build(const float* __restrict__ P0, const float* __restrict__ P3,
                        const float* __restrict__ Qbuf,
                        unsigned short* __restrict__ W1, unsigned short* __restrict__ W2) {
  int t = blockIdx.x * blockDim.x + threadIdx.x;
  if (t >= 131072) return;
  const float* Q1 = Qbuf;
  const float* Q2 = Qbuf + 16384;
  int e  = t & 65535;
  int r  = e & 7;
  int l  = (e >> 3) & 63;
  int kx = (e >> 9) & 3;
  int mt = (e >> 11) & 1;
  int t2 = (e >> 12) & 15;
  float acc = 0.0f;
  if (t < 65536) {
    int m = mt * 32 + (l & 31);
    int q = kx * 16 + ((l >> 5) << 3) + r;
    int j0 = m >> 3, j1 = m & 7, i0 = q >> 3, i1 = q & 7;
    #pragma unroll
    for (int t1 = 0; t1 < 16; ++t1) {
      float c0 = P0[(j0 * 8 + (t1 >> 1)) * 16 + ((t1 & 1) * 8 + i0)];
      int a1 = j1 * 16 + t2, u1 = t1 * 8 + i1;
      float c1 = Q1[((a1 & 7) * 8 + (u1 >> 4)) * 256 + (a1 >> 3) * 16 + (u1 & 15)];
      acc += c0 * c1;
    }
    W1[e] = f2bits(acc);
  } else {
    int n = mt * 32 + (l & 31);
    int s = kx * 16 + (r & 3) + 8 * (r >> 2) + 4 * (l >> 5);   // sigma-permuted k-map
    int j2 = n >> 3, j3 = n & 7, i2 = s >> 3, i3 = s & 7;
    #pragma unroll
    for (int t3 = 0; t3 < 16; ++t3) {
      int a2 = j2 * 16 + t3, u2 = t2 * 8 + i2;
      float c2 = Q2[((a2 & 7) * 8 + (u2 >> 4)) * 256 + (a2 >> 3) * 16 + (u2 & 15)];
      float c3 = P3[((t3 & 7) * 8 + i3) * 16 + (j3 * 2 + (t3 >> 3))];
      acc += c2 * c3;
    }
    W2[e] = f2bits(acc);
  }
}

// ---------------------------------------------------------------------------
// Kernel 3 (R6 base + swap-free pack). WG = 4 waves / 4 batch elems. Wave w:
// elem pair ep=(w>>1)*2..+1, m-half mh=w&1. Per t2: 32 MFMA over 2 elems
// sharing one weight set; b2 loads at iter top, b1 reloads mid-iter (L2
// latency hidden). Pack = 8x v_cvt_pk_bf16_f32 per element (sigma baked
// into W2), no cross-lane ops. Peak live set ~230 regs @ 2 waves/SIMD.
// ---------------------------------------------------------------------------
__global__ __launch_bounds__(256, 2) void k_main(
    const float* __restrict__ x,
    const unsigned short* __restrict__ W1,
    const unsigned short* __restrict__ W2,
    const float* __restrict__ bias,
    float* __restrict__ out) {
  __shared__ __align__(16) char XsT[4 * 8192];   // [elem][64 s][128 B], swizzled

  const int tid  = threadIdx.x;
  const int lane = tid & 63;
  const int w    = tid >> 6;
  const int h    = lane >> 5;
  const int l31  = lane & 31;
  const int ep   = (w >> 1) * 2;   // first elem of this wave's pair
  const int mh   = w & 1;          // m-half this wave owns
  const size_t bbase = (size_t)blockIdx.x * 4;

  // ---- Wave w stages elem w (f32 -> bf16, [s][q] transposed, swizzled) ----
  {
    const int s = lane;
    const float* xb = x + (bbase + w) * 4096;
    const unsigned sw = ((unsigned)(s & 7)) << 4;
    char* base = XsT + w * 8192 + s * 128;
    #pragma unroll
    for (int c = 0; c < 4; ++c) {               // 16 q per chunk
      unsigned int d[8];
      #pragma unroll
      for (int jj = 0; jj < 8; ++jj) {
        float a  = xb[(c * 16 + 2 * jj + 0) * 64 + s];
        float bq = xb[(c * 16 + 2 * jj + 1) * 64 + s];
        d[jj] = pkcvt(a, bq);
      }
      u32x4 v0 = {d[0], d[1], d[2], d[3]};
      u32x4 v1 = {d[4], d[5], d[6], d[7]};
      *(u32x4*)(base + (((unsigned)(c * 32)) ^ sw))      = v0;
      *(u32x4*)(base + (((unsigned)(c * 32 + 16)) ^ sw)) = v1;
    }
  }
  __syncthreads();

  // ---- Hoist GEMM1 A-frags for both elems (loop-invariant): 16 ds_read_b128
  sh8 af[2][2][4];
  #pragma unroll
  for (int e = 0; e < 2; ++e) {
    const char* myX = XsT + (ep + e) * 8192;
    #pragma unroll
    for (int st = 0; st < 2; ++st)
      #pragma unroll
      for (int kq = 0; kq < 4; ++kq) {
        int srow = st * 32 + l31;
        unsigned boff = (unsigned)srow * 128 +
                        (((unsigned)(kq * 32 + h * 16)) ^ (((unsigned)(srow & 7)) << 4));
        af[e][st][kq] = *(const sh8*)(myX + boff);
      }
  }

  const fx16 zc = fzero16();
  fx16 accO[2][2];                 // [elem][nt]
  accO[0][0] = zc; accO[0][1] = zc;
  accO[1][0] = zc; accO[1][1] = zc;

  const sh8* w1f = (const sh8*)W1;   // idx: t2*512 + (tile*4+kstep)*64 + lane
  const sh8* w2f = (const sh8*)W2;

  // ---- prologue: b1 for t2=0 (single-buffered, reloaded mid-iteration) ----
  sh8 b1[4];
  #pragma unroll
  for (int kq = 0; kq < 4; ++kq)
    b1[kq] = w1f[(mh * 4 + kq) * 64 + lane];

  #pragma unroll 1
  for (int t2 = 0; t2 < 16; ++t2) {
    // ---- top: b2 loads for THIS t2 (first use ~16 MFMA later) ----
    sh8 b2[2][4];
    #pragma unroll
    for (int nt = 0; nt < 2; ++nt)
      #pragma unroll
      for (int ks = 0; ks < 4; ++ks)
        b2[nt][ks] = w2f[t2 * 512 + (nt * 4 + ks) * 64 + lane];

    // ---- GEMM1 elem0: 8 MFMA, 2 chains (st-alternating) ----
    fx16 accY[2];
    __builtin_amdgcn_s_setprio(1);
    accY[0] = __builtin_amdgcn_mfma_f32_32x32x16_bf16(af[0][0][0], b1[0], zc, 0, 0, 0);
    accY[1] = __builtin_amdgcn_mfma_f32_32x32x16_bf16(af[0][1][0], b1[0], zc, 0, 0, 0);
    #pragma unroll
    for (int kq = 1; kq < 4; ++kq) {
      accY[0] = __builtin_amdgcn_mfma_f32_32x32x16_bf16(af[0][0][kq], b1[kq], accY[0], 0, 0, 0);
      accY[1] = __builtin_amdgcn_mfma_f32_32x32x16_bf16(af[0][1][kq], b1[kq], accY[1], 0, 0, 0);
    }
    __builtin_amdgcn_s_setprio(0);

    // ---- pack elem0 -> ga0: 16x cvt_pk, regs in order (sigma in W2) ----
    sh8 ga0[4];
    #pragma unroll
    for (int st = 0; st < 2; ++st) {
      fx16 Y = accY[st];
      union { u32x4 u; sh8 s8; } c0, c1;
      c0.u = (u32x4){pkcvt(Y[0], Y[1]),  pkcvt(Y[2], Y[3]),
                     pkcvt(Y[4], Y[5]),  pkcvt(Y[6], Y[7])};
      c1.u = (u32x4){pkcvt(Y[8], Y[9]),  pkcvt(Y[10], Y[11]),
                     pkcvt(Y[12], Y[13]), pkcvt(Y[14], Y[15])};
      ga0[st * 2 + 0] = c0.s8;
      ga0[st * 2 + 1] = c1.s8;
    }

    // ---- GEMM1 elem1: 8 MFMA, 2 chains; last reads of b1[cur] ----
    fx16 accZ[2];
    __builtin_amdgcn_s_setprio(1);
    accZ[0] = __builtin_amdgcn_mfma_f32_32x32x16_bf16(af[1][0][0], b1[0], zc, 0, 0, 0);
    accZ[1] = __builtin_amdgcn_mfma_f32_32x32x16_bf16(af[1][1][0], b1[0], zc, 0, 0, 0);
    #pragma unroll
    for (int kq = 1; kq < 4; ++kq) {
      accZ[0] = __builtin_amdgcn_mfma_f32_32x32x16_bf16(af[1][0][kq], b1[kq], accZ[0], 0, 0, 0);
      accZ[1] = __builtin_amdgcn_mfma_f32_32x32x16_bf16(af[1][1][kq], b1[kq], accZ[1], 0, 0, 0);
    }
    __builtin_amdgcn_s_setprio(0);

    // ---- reload b1 for t2+1 (WAR after GEMM1-e1; covered by 16 MFMA) ----
    {
      const int t2n = (t2 + 1) & 15;
      #pragma unroll
      for (int kq = 0; kq < 4; ++kq)
        b1[kq] = w1f[t2n * 512 + (mh * 4 + kq) * 64 + lane];
    }

    // ---- GEMM2 elem0: 8 MFMA, 2 chains (nt-alternating) ----
    __builtin_amdgcn_s_setprio(1);
    #pragma unroll
    for (int ks = 0; ks < 4; ++ks) {
      accO[0][0] = __builtin_amdgcn_mfma_f32_32x32x16_bf16(ga0[ks], b2[0][ks], accO[0][0], 0, 0, 0);
      accO[0][1] = __builtin_amdgcn_mfma_f32_32x32x16_bf16(ga0[ks], b2[1][ks], accO[0][1], 0, 0, 0);
    }
    __builtin_amdgcn_s_setprio(0);

    // ---- pack elem1 -> ga1 (overlaps GEMM2-e0 drain) ----
    sh8 ga1[4];
    #pragma unroll
    for (int st = 0; st < 2; ++st) {
      fx16 Y = accZ[st];
      union { u32x4 u; sh8 s8; } c0, c1;
      c0.u = (u32x4){pkcvt(Y[0], Y[1]),  pkcvt(Y[2], Y[3]),
                     pkcvt(Y[4], Y[5]),  pkcvt(Y[6], Y[7])};
      c1.u = (u32x4){pkcvt(Y[8], Y[9]),  pkcvt(Y[10], Y[11]),
                     pkcvt(Y[12], Y[13]), pkcvt(Y[14], Y[15])};
      ga1[st * 2 + 0] = c0.s8;
      ga1[st * 2 + 1] = c1.s8;
    }

    // ---- GEMM2 elem1: 8 MFMA, 2 chains ----
    __builtin_amdgcn_s_setprio(1);
    #pragma unroll
    for (int ks = 0; ks < 4; ++ks) {
      accO[1][0] = __builtin_amdgcn_mfma_f32_32x32x16_bf16(ga1[ks], b2[0][ks], accO[1][0], 0, 0, 0);
      accO[1][1] = __builtin_amdgcn_mfma_f32_32x32x16_bf16(ga1[ks], b2[1][ks], accO[1][1], 0, 0, 0);
    }
    __builtin_amdgcn_s_setprio(0);
  }

  // ---- epilogue ----
  #pragma unroll
  for (int e = 0; e < 2; ++e) {
    float* ob = out + (bbase + ep + e) * 4096;
    #pragma unroll
    for (int nt = 0; nt < 2; ++nt) {
      #pragma unroll
      for (int reg = 0; reg < 16; ++reg) {
        int m = mh * 32 + (reg & 3) + 8 * (reg >> 2) + 4 * h;
        int n = nt * 32 + l31;
        int o = m * 64 + n;
        ob[o] = accO[e][nt][reg] + bias[o];
      }
    }
  }
}

// ---------------------------------------------------------------------------
extern "C" void kernel_launch(void* const* d_in, const int* in_sizes, int n_in,
                              void* d_out, int out_size, void* d_ws, size_t ws_size,
                              hipStream_t stream) {
  (void)n_in; (void)out_size; (void)ws_size;
  const float* x    = (const float*)d_in[0];
  const float* P0   = (const float*)d_in[1];
  const float* P1   = (const float*)d_in[2];
  const float* P2   = (const float*)d_in[3];
  const float* P3   = (const float*)d_in[4];
  const float* bias = (const float*)d_in[5];
  float* out = (float*)d_out;

  // ws: Qbuf f32[128*256] (128 KB) | W1 bf16[65536] (128 KB) | W2 bf16[65536] (128 KB)
  float* Qbuf = (float*)d_ws;
  unsigned short* W1 = (unsigned short*)((char*)d_ws + 131072);
  unsigned short* W2 = (unsigned short*)((char*)d_ws + 262144);

  k_cayley<<<8, 256, 0, stream>>>(P1, P2, Qbuf);
  k_build<<<512, 256, 0, stream>>>(P0, P3, Qbuf, W1, W2);

  int batch = in_sizes[0] / 4096;
  k_main<<<batch / 4, 256, 0, stream>>>(x, W1, W2, bias, out);
}